// Round 1
// baseline (1153.238 us; speedup 1.0000x reference)
//
#include <hip/hip_runtime.h>

// SAGEConv (mean aggr, root weight, L2 normalize), fp32.
// inputs: edge_index[2,E] int32, x[N,96] f32, W_l[128,96] f32, b_l[128] f32, W_r[128,96] f32
// output: [N,128] f32 row-normalized.

constexpr int kNodes = 50000;
constexpr int kEdges = 800000;
constexpr int kF = 96;    // input features
constexpr int kH = 128;   // hidden/output features
constexpr int kChunks = kF / 4;  // 24 float4 chunks per edge

// --- Kernel 1: scatter mean numerator + degree -------------------------------
// One thread per (edge, float4 chunk). Gather x[src] row, atomic-add into
// msg[dst]. Chunk 0's thread also bumps deg[dst].
__global__ void __launch_bounds__(256)
scatter_kernel(const int* __restrict__ ei, const float* __restrict__ x,
               float* __restrict__ msg, float* __restrict__ deg) {
  int tid = blockIdx.x * 256 + threadIdx.x;
  int e = tid / kChunks;
  if (e >= kEdges) return;
  int c = tid - e * kChunks;

  int src = ei[e];            // row 0 of edge_index
  int dst = ei[kEdges + e];   // row 1

  const float4 v = *reinterpret_cast<const float4*>(x + (size_t)src * kF + c * 4);
  float* m = msg + (size_t)dst * kF + c * 4;
  atomicAdd(m + 0, v.x);
  atomicAdd(m + 1, v.y);
  atomicAdd(m + 2, v.z);
  atomicAdd(m + 3, v.w);
  if (c == 0) atomicAdd(deg + dst, 1.0f);
}

// --- Kernel 2: out = (msg/deg) @ Wl^T + bl + x @ Wr^T, then L2-normalize -----
// Weights staged transposed in LDS: sW[f][h]. One wave per node; lane l owns
// output channels l and l+64. LDS rows are lane-consecutive -> conflict-free.
__global__ void __launch_bounds__(1024)
sage_out_kernel(const float* __restrict__ x, const float* __restrict__ msg,
                const float* __restrict__ deg,
                const float* __restrict__ Wl, const float* __restrict__ bl,
                const float* __restrict__ Wr, float* __restrict__ out) {
  __shared__ float sWl[kF][kH + 1];  // +1 pad: conflict-free transposed store
  __shared__ float sWr[kF][kH + 1];

  for (int i = threadIdx.x; i < kF * kH; i += 1024) {
    int h = i / kF;
    int f = i - h * kF;
    sWl[f][h] = Wl[i];   // W is [kH][kF] row-major
    sWr[f][h] = Wr[i];
  }
  __syncthreads();

  const int wave = threadIdx.x >> 6;
  const int lane = threadIdx.x & 63;
  const float b0 = bl[lane];
  const float b1 = bl[lane + 64];

  for (int node = blockIdx.x * 16 + wave; node < kNodes; node += gridDim.x * 16) {
    const float inv = 1.0f / fmaxf(deg[node], 1.0f);
    const float* __restrict__ xr = x + (size_t)node * kF;
    const float* __restrict__ mr = msg + (size_t)node * kF;

    float acc0 = b0, acc1 = b1;
#pragma unroll 8
    for (int f = 0; f < kF; ++f) {
      const float a  = mr[f] * inv;  // uniform address -> broadcast load
      const float xv = xr[f];
      acc0 += a * sWl[f][lane]      + xv * sWr[f][lane];
      acc1 += a * sWl[f][lane + 64] + xv * sWr[f][lane + 64];
    }

    // wave-wide sum of squares for the row L2 norm
    float ss = acc0 * acc0 + acc1 * acc1;
#pragma unroll
    for (int off = 32; off >= 1; off >>= 1) ss += __shfl_xor(ss, off, 64);
    const float scale = 1.0f / fmaxf(sqrtf(ss), 1e-12f);

    float* o = out + (size_t)node * kH;
    o[lane]      = acc0 * scale;
    o[lane + 64] = acc1 * scale;
  }
}

extern "C" void kernel_launch(void* const* d_in, const int* in_sizes, int n_in,
                              void* d_out, int out_size, void* d_ws, size_t ws_size,
                              hipStream_t stream) {
  const int*   ei = (const int*)d_in[0];
  const float* x  = (const float*)d_in[1];
  const float* Wl = (const float*)d_in[2];
  const float* bl = (const float*)d_in[3];
  const float* Wr = (const float*)d_in[4];
  float* out = (float*)d_out;

  float* msg = (float*)d_ws;                       // [kNodes*kF]
  float* deg = msg + (size_t)kNodes * kF;          // [kNodes]
  const size_t zero_bytes = ((size_t)kNodes * kF + kNodes) * sizeof(float);
  hipMemsetAsync(d_ws, 0, zero_bytes, stream);

  const int scatter_threads = kEdges * kChunks;    // 19.2M
  const int scatter_blocks = (scatter_threads + 255) / 256;
  scatter_kernel<<<scatter_blocks, 256, 0, stream>>>(ei, x, msg, deg);

  sage_out_kernel<<<512, 1024, 0, stream>>>(x, msg, deg, Wl, bl, Wr, out);
}

// Round 2
// 387.794 us; speedup vs baseline: 2.9738x; 2.9738x over previous
//
#include <hip/hip_runtime.h>

// SAGEConv (mean aggr, root weight, L2 normalize), fp32.
// Strategy: build CSR (counting sort) -> fused pull-aggregate + dual GEMM + L2norm.

constexpr int kNodes = 50000;
constexpr int kEdges = 800000;
constexpr int kF = 96;    // input features
constexpr int kH = 128;   // output features

// --- Kernel 1: integer degree ------------------------------------------------
__global__ void __launch_bounds__(256)
deg_kernel(const int* __restrict__ ei, int* __restrict__ degi) {
  int e = blockIdx.x * 256 + threadIdx.x;
  if (e >= kEdges) return;
  atomicAdd(&degi[ei[kEdges + e]], 1);
}

// --- Kernel 2: exclusive scan of degi -> row_start, cursor -------------------
// Single block, 1024 threads, shfl-based wave scans + LDS cross-wave combine.
__global__ void __launch_bounds__(1024)
scan_kernel(const int* __restrict__ degi, int* __restrict__ row_start,
            int* __restrict__ cursor) {
  __shared__ int wsum[16];
  __shared__ int carry_s;
  const int tid = threadIdx.x, wave = tid >> 6, lane = tid & 63;
  if (tid == 0) carry_s = 0;
  __syncthreads();
  for (int base = 0; base < kNodes; base += 1024) {
    const int i = base + tid;
    const int v = (i < kNodes) ? degi[i] : 0;
    // wave-inclusive scan
    int sc = v;
#pragma unroll
    for (int off = 1; off < 64; off <<= 1) {
      int t = __shfl_up(sc, off, 64);
      if (lane >= off) sc += t;
    }
    if (lane == 63) wsum[wave] = sc;
    __syncthreads();
    int woff = 0;
#pragma unroll
    for (int w = 0; w < 16; ++w) woff += (w < wave) ? wsum[w] : 0;
    const int excl = carry_s + woff + sc - v;
    if (i < kNodes) { row_start[i] = excl; cursor[i] = excl; }
    __syncthreads();
    if (tid == 1023) carry_s += woff + sc;  // chunk total
    __syncthreads();
  }
  if (tid == 0) row_start[kNodes] = carry_s;  // == kEdges
}

// --- Kernel 3: fill CSR slots ------------------------------------------------
__global__ void __launch_bounds__(256)
fill_kernel(const int* __restrict__ ei, int* __restrict__ cursor,
            int* __restrict__ csr_src) {
  int e = blockIdx.x * 256 + threadIdx.x;
  if (e >= kEdges) return;
  const int dst = ei[kEdges + e];
  const int slot = atomicAdd(&cursor[dst], 1);
  csr_src[slot] = ei[e];
}

// --- Kernel 4: fused aggregate + out = agg@Wl^T + bl + x@Wr^T, L2-normalize --
// One wave per node. Weights transposed in LDS (sW[f][h], +1 pad).
// Gather: lane l accumulates feature l (all 64) and feature 64+l (lanes<32).
__global__ void __launch_bounds__(1024)
fused_kernel(const float* __restrict__ x, const int* __restrict__ row_start,
             const int* __restrict__ csr_src,
             const float* __restrict__ Wl, const float* __restrict__ bl,
             const float* __restrict__ Wr, float* __restrict__ out) {
  __shared__ float sWl[kF][kH + 1];
  __shared__ float sWr[kF][kH + 1];
  __shared__ float sAgg[16][kF];

  for (int i = threadIdx.x; i < kF * kH; i += 1024) {
    int h = i / kF;
    int f = i - h * kF;
    sWl[f][h] = Wl[i];   // W is [kH][kF] row-major
    sWr[f][h] = Wr[i];
  }
  __syncthreads();

  const int wave = threadIdx.x >> 6;
  const int lane = threadIdx.x & 63;
  const float b0 = bl[lane];
  const float b1 = bl[lane + 64];

  for (int node = blockIdx.x * 16 + wave; node < kNodes; node += gridDim.x * 16) {
    const int s = row_start[node];
    const int e = row_start[node + 1];
    float a0 = 0.f, a1 = 0.f;
    for (int i = s; i < e; ++i) {
      const int src = csr_src[i];
      const float* __restrict__ xr = x + (size_t)src * kF;
      a0 += xr[lane];
      if (lane < 32) a1 += xr[64 + lane];
    }
    const float inv = 1.0f / fmaxf((float)(e - s), 1.0f);
    sAgg[wave][lane] = a0 * inv;
    if (lane < 32) sAgg[wave][64 + lane] = a1 * inv;
    // same-wave LDS write->read: compiler-inserted lgkmcnt ordering suffices

    const float* __restrict__ xr = x + (size_t)node * kF;
    float acc0 = b0, acc1 = b1;
#pragma unroll 8
    for (int f = 0; f < kF; ++f) {
      const float a  = sAgg[wave][f];   // uniform -> LDS broadcast
      const float xv = xr[f];
      acc0 += a * sWl[f][lane]      + xv * sWr[f][lane];
      acc1 += a * sWl[f][lane + 64] + xv * sWr[f][lane + 64];
    }

    float ss = acc0 * acc0 + acc1 * acc1;
#pragma unroll
    for (int off = 32; off >= 1; off >>= 1) ss += __shfl_xor(ss, off, 64);
    const float scale = 1.0f / fmaxf(sqrtf(ss), 1e-12f);

    float* o = out + (size_t)node * kH;
    o[lane]      = acc0 * scale;
    o[lane + 64] = acc1 * scale;
  }
}

extern "C" void kernel_launch(void* const* d_in, const int* in_sizes, int n_in,
                              void* d_out, int out_size, void* d_ws, size_t ws_size,
                              hipStream_t stream) {
  const int*   ei = (const int*)d_in[0];
  const float* x  = (const float*)d_in[1];
  const float* Wl = (const float*)d_in[2];
  const float* bl = (const float*)d_in[3];
  const float* Wr = (const float*)d_in[4];
  float* out = (float*)d_out;

  int* degi      = (int*)d_ws;                 // [kNodes]
  int* row_start = degi + kNodes;              // [kNodes+1]
  int* cursor    = row_start + kNodes + 1;     // [kNodes+1]
  int* csr_src   = cursor + kNodes + 1;        // [kEdges]

  hipMemsetAsync(degi, 0, kNodes * sizeof(int), stream);

  const int eblocks = (kEdges + 255) / 256;
  deg_kernel<<<eblocks, 256, 0, stream>>>(ei, degi);
  scan_kernel<<<1, 1024, 0, stream>>>(degi, row_start, cursor);
  fill_kernel<<<eblocks, 256, 0, stream>>>(ei, cursor, csr_src);

  const int nblocks = (kNodes + 15) / 16;
  fused_kernel<<<nblocks, 1024, 0, stream>>>(x, row_start, csr_src, Wl, bl, Wr, out);
}